// Round 7
// baseline (408.655 us; speedup 1.0000x reference)
//
#include <hip/hip_runtime.h>

// Problem constants (B,S,D,H from reference)
#define B_ 2
#define S_ 2048
#define D_ 1024
#define H_ 16
#define DK_ 64
#define M_ (B_ * S_)      // 4096 rows in the projection GEMMs

typedef __bf16 bf16;
typedef __attribute__((ext_vector_type(8))) __bf16 bf16x8;
typedef __attribute__((ext_vector_type(4))) __bf16 bf16x4;
typedef __attribute__((ext_vector_type(4))) float f32x4;

static __device__ __forceinline__ bf16x8 ld8(const bf16* p) {
    return *(const bf16x8*)p;   // 16B aligned by construction
}
static __device__ __forceinline__ bf16x8 cvt8(const float* p) {
    f32x4 a = *(const f32x4*)p, b = *(const f32x4*)(p + 4);
    bf16x8 r;
    r[0]=(bf16)a[0]; r[1]=(bf16)a[1]; r[2]=(bf16)a[2]; r[3]=(bf16)a[3];
    r[4]=(bf16)b[0]; r[5]=(bf16)b[1]; r[6]=(bf16)b[2]; r[7]=(bf16)b[3];
    return r;
}

// ---------------------------------------------------------------------------
// 128x64-tile GEMM, LDS-staged. Grid 32x16 = 512 blocks (2/CU, barriers
// overlap across blocks).  Y[m,n] = (sum_k A[m,k]*W[n,k] + bias[n]) * scale.
// A: a_mode 0 = fp32 flat (MxD, cvt in-register); 1 = bf16 head-split (ctx).
// W: fp32 (NxD), cvt in-register.
// out_mode: 0 = bf16 head-split (B,H,S,DK); 1 = fp32 flat; 2 = bf16 V^T (B,H,DK,S).
// ---------------------------------------------------------------------------
__global__ __launch_bounds__(256)
void gemm(const void* __restrict__ Av, const float* __restrict__ W,
          const float* __restrict__ bias, void* __restrict__ out,
          int a_mode, int out_mode, float scale)
{
    const int m0 = blockIdx.x * 128, n0 = blockIdx.y * 64;
    const int tid = threadIdx.x;
    const int wv = tid >> 6, lane = tid & 63, quad = lane >> 4, l16 = lane & 15;
    const int wr = (wv >> 1) * 64, wc = (wv & 1) * 32;

    __shared__ bf16 As[128 * 32];   // 8 KB
    __shared__ bf16 Bs[64 * 32];    // 4 KB

    f32x4 acc[4][2];
#pragma unroll
    for (int i = 0; i < 4; ++i)
#pragma unroll
        for (int j = 0; j < 2; ++j) acc[i][j] = f32x4{0.f,0.f,0.f,0.f};

    const int ar = tid >> 1, ac = (tid & 1) * 16;   // A: 16 elems/thread
    const int br = tid >> 2, bc = (tid & 3) * 8;    // B: 8 elems/thread

    for (int k0 = 0; k0 < D_; k0 += 32) {
        bf16x8 a0, a1, b0;
        if (a_mode == 0) {
            const float* ap = (const float*)Av + (size_t)(m0 + ar) * D_ + k0 + ac;
            a0 = cvt8(ap); a1 = cvt8(ap + 8);
        } else {
            const int m = m0 + ar, bb = m >> 11, ss = m & (S_ - 1);
            const int k = k0 + ac, hh = k >> 6, dd = k & (DK_ - 1);
            const bf16* ap = (const bf16*)Av +
                ((size_t)(bb * H_ + hh) * S_ + ss) * DK_ + dd;  // 16-seg never crosses head
            a0 = ld8(ap); a1 = ld8(ap + 8);
        }
        b0 = cvt8(W + (size_t)(n0 + br) * D_ + k0 + bc);

        __syncthreads();
        *(bf16x8*)(As + ar*32 + ac)     = a0;
        *(bf16x8*)(As + ar*32 + ac + 8) = a1;
        *(bf16x8*)(Bs + br*32 + bc)     = b0;
        __syncthreads();

        bf16x8 af[4], bfr[2];
#pragma unroll
        for (int i = 0; i < 4; ++i)
            af[i] = *(const bf16x8*)(As + (wr + i*16 + l16) * 32 + quad * 8);
#pragma unroll
        for (int j = 0; j < 2; ++j)
            bfr[j] = *(const bf16x8*)(Bs + (wc + j*16 + l16) * 32 + quad * 8);
#pragma unroll
        for (int i = 0; i < 4; ++i)
#pragma unroll
            for (int j = 0; j < 2; ++j)
                acc[i][j] = __builtin_amdgcn_mfma_f32_16x16x32_bf16(
                    af[i], bfr[j], acc[i][j], 0, 0, 0);
    }

#pragma unroll
    for (int i = 0; i < 4; ++i)
#pragma unroll
        for (int j = 0; j < 2; ++j) {
            const int nn = n0 + wc + j*16 + l16;
            const float bvv = bias[nn];
            const int mm0 = m0 + wr + i*16 + quad*4;   // 4-aligned, same batch
            if (out_mode == 2) {
                bf16x4 pk;
#pragma unroll
                for (int r = 0; r < 4; ++r) pk[r] = (bf16)((acc[i][j][r] + bvv) * scale);
                const int bb = mm0 >> 11, ss = mm0 & (S_ - 1);
                const int hh = nn >> 6,  dd = nn & (DK_ - 1);
                *(bf16x4*)((bf16*)out + ((size_t)(bb * H_ + hh) * DK_ + dd) * S_ + ss) = pk;
            } else {
#pragma unroll
                for (int r = 0; r < 4; ++r) {
                    const int mm = mm0 + r;
                    const float v = (acc[i][j][r] + bvv) * scale;
                    if (out_mode == 1) {
                        ((float*)out)[(size_t)mm * D_ + nn] = v;
                    } else {
                        const int bb = mm >> 11, ss = mm & (S_ - 1);
                        const int hh = nn >> 6, dd = nn & (DK_ - 1);
                        ((bf16*)out)[((size_t)(bb * H_ + hh) * S_ + ss) * DK_ + dd] = (bf16)v;
                    }
                }
            }
        }
}

// ---------------------------------------------------------------------------
// Flash context: block = (q-tile64, head, b). Single QK^T pass accumulates
// unnormalized P~V (registers) AND row-sums lsum; epilogue normalizes and
// emits Linv for attn_weights. Q is pre-scaled by 1/8 at projection.
// Wave w owns j in [512w, 512w+512); K/V^T frags feed 4 q-tiles.
// ---------------------------------------------------------------------------
__global__ __launch_bounds__(256)
void attn_ctx(const bf16* __restrict__ Q, const bf16* __restrict__ K,
              const bf16* __restrict__ Vt, bf16* __restrict__ ctxOut,
              float* __restrict__ LinvOut)
{
    const int q0 = blockIdx.x * 64, h = blockIdx.y, b = blockIdx.z;
    const int tid = threadIdx.x;
    const int wv = tid >> 6, lane = tid & 63, quad = lane >> 4, l16 = lane & 15;

    __shared__ __align__(16) bf16 Pw[4][4][16][40];  // [wv][qt][q16][j32+pad] 20.5 KB
    __shared__ float ctxp[4][64*17 + 16];            // 17.5 KB
    __shared__ float wp[4][4][16];                   // 1 KB
    __shared__ float linvS[64];

    const size_t hb = (size_t)(b * H_ + h) * S_;
    bf16x8 qf[4][2];
#pragma unroll
    for (int qt = 0; qt < 4; ++qt) {
        const bf16* qrow = Q + (hb + q0 + qt*16 + l16) * DK_;
        qf[qt][0] = ld8(qrow + quad*8);
        qf[qt][1] = ld8(qrow + 32 + quad*8);
    }
    const bf16* Kb  = K  + hb * DK_;
    const bf16* Vtb = Vt + hb * DK_;

    f32x4 cacc[4][4];   // [db][qt]
    float lsum[4][4];   // [qt][r]
#pragma unroll
    for (int a = 0; a < 4; ++a)
#pragma unroll
        for (int c = 0; c < 4; ++c) { cacc[a][c] = f32x4{0.f,0.f,0.f,0.f}; lsum[a][c] = 0.f; }

    for (int jc = 0; jc < 16; ++jc) {
        const int j0 = wv * 512 + jc * 32;
        const bf16* kr0 = Kb + (size_t)(j0 + l16) * DK_;
        const bf16* kr1 = Kb + (size_t)(j0 + 16 + l16) * DK_;
        bf16x8 kf0a = ld8(kr0 + quad*8), kf0b = ld8(kr0 + 32 + quad*8);
        bf16x8 kf1a = ld8(kr1 + quad*8), kf1b = ld8(kr1 + 32 + quad*8);

#pragma unroll
        for (int qt = 0; qt < 4; ++qt) {
            f32x4 z0 = {0.f,0.f,0.f,0.f}, z1 = {0.f,0.f,0.f,0.f};
            z0 = __builtin_amdgcn_mfma_f32_16x16x32_bf16(qf[qt][0], kf0a, z0, 0, 0, 0);
            f32x4 s0 = __builtin_amdgcn_mfma_f32_16x16x32_bf16(qf[qt][1], kf0b, z0, 0, 0, 0);
            z1 = __builtin_amdgcn_mfma_f32_16x16x32_bf16(qf[qt][0], kf1a, z1, 0, 0, 0);
            f32x4 s1 = __builtin_amdgcn_mfma_f32_16x16x32_bf16(qf[qt][1], kf1b, z1, 0, 0, 0);
#pragma unroll
            for (int r = 0; r < 4; ++r) {
                const float e0 = __expf(fminf(s0[r], 60.f));
                const float e1 = __expf(fminf(s1[r], 60.f));
                lsum[qt][r] += e0 + e1;
                Pw[wv][qt][quad*4 + r][l16]      = (bf16)e0;
                Pw[wv][qt][quad*4 + r][16 + l16] = (bf16)e1;
            }
        }
#pragma unroll
        for (int db = 0; db < 4; ++db) {
            bf16x8 va = ld8(Vtb + (size_t)(db*16 + l16) * S_ + j0 + quad*8);
#pragma unroll
            for (int qt = 0; qt < 4; ++qt) {
                bf16x8 pa = *(const bf16x8*)&Pw[wv][qt][l16][quad*8];
                cacc[db][qt] = __builtin_amdgcn_mfma_f32_16x16x32_bf16(
                    va, pa, cacc[db][qt], 0, 0, 0);
            }
        }
    }

    // reduce lsum: lanes (l16) -> waves
#pragma unroll
    for (int d = 1; d < 16; d <<= 1)
#pragma unroll
        for (int qt = 0; qt < 4; ++qt)
#pragma unroll
            for (int r = 0; r < 4; ++r)
                lsum[qt][r] += __shfl_xor(lsum[qt][r], d);
    if (l16 == 0)
#pragma unroll
        for (int qt = 0; qt < 4; ++qt)
#pragma unroll
            for (int r = 0; r < 4; ++r) wp[wv][qt][quad*4 + r] = lsum[qt][r];
    __syncthreads();
    if (tid < 64) {
        const int qt = tid >> 4, row = tid & 15;
        const float l = wp[0][qt][row] + wp[1][qt][row] + wp[2][qt][row] + wp[3][qt][row];
        const float li = 1.0f / fmaxf(l, 1e-30f);
        linvS[tid] = li;
        LinvOut[hb + q0 + tid] = li;
    }

    // cross-wave ctx reduce + normalize + write, one q-tile at a time
#pragma unroll
    for (int qt = 0; qt < 4; ++qt) {
        __syncthreads();
#pragma unroll
        for (int db = 0; db < 4; ++db)
#pragma unroll
            for (int r = 0; r < 4; ++r)
                ctxp[wv][(db*16 + quad*4 + r) * 17 + l16] = cacc[db][qt][r];
        __syncthreads();
        {
            const int q  = tid >> 4;
            const int d0 = (tid & 15) * 4;
            const float li = linvS[qt*16 + q];
            bf16x4 pk;
#pragma unroll
            for (int i = 0; i < 4; ++i) {
                const int e = (d0 + i) * 17 + q;
                pk[i] = (bf16)((ctxp[0][e] + ctxp[1][e] + ctxp[2][e] + ctxp[3][e]) * li);
            }
            *(bf16x4*)(ctxOut + (hb + q0 + qt*16 + q) * DK_ + d0) = pk;
        }
    }
}

// ---------------------------------------------------------------------------
// Head-mean attention weights: block = (q-tile64, j-chunk256, b).
// Q pre-scaled by 1/8; Linv precomputed by attn_ctx. No inner barriers.
// ---------------------------------------------------------------------------
__global__ __launch_bounds__(256)
void attn_weights(const bf16* __restrict__ Q, const bf16* __restrict__ K,
                  const float* __restrict__ Linv, float* __restrict__ attnOut)
{
    const int q0 = blockIdx.x * 64, j0 = blockIdx.y * 256, b = blockIdx.z;
    const int tid = threadIdx.x;
    const int wv = tid >> 6, lane = tid & 63, quad = lane >> 4, l16 = lane & 15;

    __shared__ float linv[H_][64];
#pragma unroll
    for (int i = 0; i < 4; ++i) {
        const int idx = tid * 4 + i;
        const int hh = idx >> 6, row = idx & 63;
        linv[hh][row] = Linv[(size_t)(b * H_ + hh) * S_ + q0 + row];
    }
    __syncthreads();

    f32x4 asum[4][4];
#pragma unroll
    for (int qt = 0; qt < 4; ++qt)
#pragma unroll
        for (int t = 0; t < 4; ++t) asum[qt][t] = f32x4{0.f,0.f,0.f,0.f};

    for (int h = 0; h < H_; ++h) {
        const size_t hb = (size_t)(b * H_ + h) * S_;
        bf16x8 qf[4][2];
#pragma unroll
        for (int qt = 0; qt < 4; ++qt) {
            const bf16* qrow = Q + (hb + q0 + qt*16 + l16) * DK_;
            qf[qt][0] = ld8(qrow + quad*8);
            qf[qt][1] = ld8(qrow + 32 + quad*8);
        }
        const bf16* Kb = K + hb * DK_;
#pragma unroll
        for (int t = 0; t < 4; ++t) {
            const int jl = j0 + wv*64 + t*16;
            const bf16* krow = Kb + (size_t)(jl + l16) * DK_;
            bf16x8 kf0 = ld8(krow + quad*8), kf1 = ld8(krow + 32 + quad*8);
#pragma unroll
            for (int qt = 0; qt < 4; ++qt) {
                f32x4 z = {0.f,0.f,0.f,0.f};
                z = __builtin_amdgcn_mfma_f32_16x16x32_bf16(qf[qt][0], kf0, z, 0, 0, 0);
                f32x4 s = __builtin_amdgcn_mfma_f32_16x16x32_bf16(qf[qt][1], kf1, z, 0, 0, 0);
#pragma unroll
                for (int r = 0; r < 4; ++r)
                    asum[qt][t][r] += __expf(fminf(s[r], 60.f))
                                      * linv[h][qt*16 + quad*4 + r];
            }
        }
    }
#pragma unroll
    for (int qt = 0; qt < 4; ++qt)
#pragma unroll
        for (int t = 0; t < 4; ++t)
#pragma unroll
            for (int r = 0; r < 4; ++r)
                attnOut[((size_t)b * S_ + q0 + qt*16 + quad*4 + r) * S_
                        + j0 + wv*64 + t*16 + l16] = asum[qt][t][r] * (1.0f / H_);
}

// ---------------------------------------------------------------------------
extern "C" void kernel_launch(void* const* d_in, const int* in_sizes, int n_in,
                              void* d_out, int out_size, void* d_ws, size_t ws_size,
                              hipStream_t stream)
{
    (void)in_sizes; (void)n_in; (void)out_size; (void)ws_size;

    const float* query = (const float*)d_in[0];
    const float* key_t = (const float*)d_in[1];
    const float* value = (const float*)d_in[2];
    const float* Wq = (const float*)d_in[3];
    const float* bq = (const float*)d_in[4];
    const float* Wk = (const float*)d_in[5];
    const float* bk = (const float*)d_in[6];
    const float* Wv = (const float*)d_in[7];
    const float* bv = (const float*)d_in[8];
    const float* Wo = (const float*)d_in[9];
    const float* bo = (const float*)d_in[10];

    float* out     = (float*)d_out;                  // (B,S,D) fp32
    float* attnOut = out + (size_t)B_ * S_ * D_;     // (B,S,S) fp32

    const size_t nX = (size_t)B_ * S_ * D_;
    // ws: Q,K,V^T,ctx (4 x 8.39MB bf16) + Linv (0.26MB) = 33.8 MB
    bf16* Qh   = (bf16*)d_ws;
    bf16* Kh   = Qh + nX;
    bf16* VtH  = Kh + nX;                            // V^T (B,H,DK,S)
    bf16* ctxB = VtH + nX;                           // ctx (B,H,S,DK)
    float* Linv = (float*)(ctxB + nX);

    dim3 gg(M_/128, D_/64);                          // 32 x 16 = 512 blocks
    gemm<<<gg, 256, 0, stream>>>(query, Wq, bq, Qh, 0, 0, 0.125f);  // Q pre-scaled
    gemm<<<gg, 256, 0, stream>>>(key_t, Wk, bk, Kh, 0, 0, 1.0f);
    gemm<<<gg, 256, 0, stream>>>(value, Wv, bv, VtH, 0, 2, 1.0f);   // V^T layout
    attn_ctx    <<<dim3(S_/64, H_, B_), 256, 0, stream>>>(Qh, Kh, VtH, ctxB, Linv);
    attn_weights<<<dim3(S_/64, S_/256, B_), 256, 0, stream>>>(Qh, Kh, Linv, attnOut);
    gemm<<<gg, 256, 0, stream>>>(ctxB, Wo, bo, out, 1, 1, 1.0f);
}